// Round 6
// baseline (120.435 us; speedup 1.0000x reference)
//
#include <hip/hip_runtime.h>
#include <math.h>

#define BB 512
#define DD 16
#define NN 64
#define MM 32
#define RR 32
#define CC 10
#define ISTR 40          // halves per (b,j) row: 32 i + 8 pad (80 B, 16B-aligned)
#define BSTR 1288        // halves per b region: 32*ISTR + 8 (bank de-phase pad)

typedef _Float16 v8h __attribute__((ext_vector_type(8)));
typedef float v4f __attribute__((ext_vector_type(4)));
typedef float v16f __attribute__((ext_vector_type(16)));

union H8 { unsigned int u[4]; v8h h; _Float16 e[8]; };
union H4 { unsigned int u[2]; _Float16 e[4]; };

__device__ inline unsigned pk2(float a, float b) {
    union { unsigned u; _Float16 e[2]; } v;
    v.e[0] = (_Float16)a; v.e[1] = (_Float16)b;
    return v.u;
}

// ---------------------------------------------------------------------------
// Kernel 1: merged producers (coalesced via LDS staging).
//  blocks [0,1024):   feat_h = fp16( tensor @ W + b )   [B][D][M]
//  blocks [1024,1344): per (c,d,half-slab): G -> gh in 32x32x16 B-frag order:
//    tile t = i*2 + ks  (i in [0,32), ks = K-step)
//    gh[(((c*16+d)*64 + t)*64 + lane)*8 + r] =
//        fp16( G[c][d][i][ m = 16*ks + 8*(lane>>5) + r ][ j = lane&31 ] )
// ---------------------------------------------------------------------------
__global__ __launch_bounds__(256) void produce_kernel(
    const float* __restrict__ tensor, const float* __restrict__ W,
    const float* __restrict__ bias,   const float* __restrict__ G,
    _Float16* __restrict__ fh,        _Float16* __restrict__ gh) {
    __shared__ __align__(16) char smem[36864];
    const int t = threadIdx.x;
    if (blockIdx.x < 1024) {
        float* ten_s = (float*)smem;          // [8][64]
        float* W_s   = (float*)smem + 512;    // [64][32]
        const int bd0 = blockIdx.x * 8;
        if (t < 128)
            *(float4*)(ten_s + t * 4) = *(const float4*)(tensor + bd0 * NN + t * 4);
        *(float4*)(W_s + t * 4)        = *(const float4*)(W + t * 4);
        *(float4*)(W_s + 1024 + t * 4) = *(const float4*)(W + 1024 + t * 4);
        __syncthreads();
        const int m = t & 31, bd_l = t >> 5;
        float acc = bias[m];
#pragma unroll
        for (int n = 0; n < NN; ++n) acc += ten_s[bd_l * NN + n] * W_s[n * MM + m];
        fh[(bd0 + bd_l) * MM + m] = (_Float16)acc;
    } else {
        _Float16* lg = (_Float16*)smem;       // [di][m][j], m-stride 36 halves
        const int pb = blockIdx.x - 1024;     // 0..319
        const int c  = pb >> 5;
        const int d  = (pb >> 1) & 15;
        const int hf = pb & 1;
        const float* src = G + (size_t)(c * DD + d) * 32768 + hf * 16384;
#pragma unroll
        for (int k = 0; k < 16; ++k) {        // coalesced read of 64 KB slab-half
            const int f = (k * 256 + t) * 4;
            float4 v = *(const float4*)(src + f);
            const int di = f >> 10, m = (f >> 5) & 31, j = f & 31;
            H4 hv;
            hv.e[0] = (_Float16)v.x; hv.e[1] = (_Float16)v.y;
            hv.e[2] = (_Float16)v.z; hv.e[3] = (_Float16)v.w;
            *(uint2*)(lg + di * 1152 + m * 36 + j) = make_uint2(hv.u[0], hv.u[1]);
        }
        __syncthreads();
#pragma unroll
        for (int k = 0; k < 8; ++k) {         // coalesced 16B fragment writes
            const int idx = k * 256 + t;
            const int tl = idx >> 6, ln = idx & 63;   // tl = di*2 + ks
            const int di = tl >> 1, ks = tl & 1;
            const int hh = ln >> 5, j = ln & 31;
            H8 o;
#pragma unroll
            for (int r = 0; r < 8; ++r)
                o.e[r] = lg[di * 1152 + (16 * ks + 8 * hh + r) * 36 + j];
            const size_t gi = ((size_t)(c * DD + d) * 64 + hf * 32 + tl) * 64 + ln;
            *(v8h*)(gh + gi * 8) = o.h;
        }
    }
}

// ---------------------------------------------------------------------------
// Kernel 2 (fused, 32x32 MFMA, register-resident state):
// per (c, b-block of 32): all 16 d's + trace. Transposed recurrence
// S_d = C_d^T * S_{d-1}; S_15 = Ptot^T; logits = diag-sum of S_15.
//  phase 1: wave w computes cores C_d[i][j] for i=4w..4w+3 via 32x32x16
//    (A = feat rows for all 32 b's, B = gh frags), packs to LDS L[b][j][i].
//  phase 2: per chain (4/wave): A = C_d^T from two b128 reads of L;
//    B = state, held in 8 VGPRs. The C-layout output differs from the
//    B-frag layout only by a lane<->lane+32 half exchange, done with
//    __shfl_xor(.,32) + select — NO LDS round trip for the state.
// Grid 160 (uniform 1 block/CU); same-c blocks pinned per XCD for L2 reuse.
// ---------------------------------------------------------------------------
__global__ __launch_bounds__(512, 2) void chain_kernel(
    const _Float16* __restrict__ feat_h,
    const _Float16* __restrict__ g_h,
    float* __restrict__ trout)         // [B][C] fp32 traces
{
    __shared__ __align__(16) _Float16 lds[32 * BSTR];   // 82432 B

    const int bid = blockIdx.x;        // 0..159
    const int xcd = bid & 7;
    const int idx = bid >> 3;          // 0..19
    int c, sub;
    if (idx < 16) { c = xcd; sub = idx; }
    else {
        const int e = idx - 16;        // 0..3
        c = 8 + (xcd >> 2);            // c8 on XCD 0-3, c9 on XCD 4-7
        sub = (xcd & 3) * 4 + e;       // 0..15
    }
    const int b0 = sub * 32;
    const int t    = threadIdx.x;
    const int w    = t >> 6;           // wave 0..7
    const int lane = t & 63;
    const int h    = lane >> 5;        // lane half
    const int col  = lane & 31;

    const size_t gc = (size_t)c * DD * 32768;
    const _Float16* fb = feat_h + (size_t)(b0 + col) * (DD * MM);

    const v16f z16 = {0.f,0.f,0.f,0.f,0.f,0.f,0.f,0.f,
                      0.f,0.f,0.f,0.f,0.f,0.f,0.f,0.f};

    // prefetch d=0 fragments
    v8h af[2];                         // feat A-frags (32 b rows), per K-step
#pragma unroll
    for (int ks = 0; ks < 2; ++ks)
        af[ks] = *(const v8h*)(fb + 16 * ks + 8 * h);
    v8h gB[4][2];                      // G B-frags, i = 4w+il, per K-step
#pragma unroll
    for (int il = 0; il < 4; ++il)
#pragma unroll
        for (int ks = 0; ks < 2; ++ks)
            gB[il][ks] = *(const v8h*)(g_h + gc +
                ((size_t)(((4 * w + il) * 2 + ks) * 64) + lane) * 8);

    v8h sb[4][2];                      // [chain cc][K-step] state B-frags

    for (int d = 0; d < DD; ++d) {
        __syncthreads();   // WAR: previous phase-2 A-reads of lds done
        // ---- phase 1: cores for i = 4w..4w+3 (2 K-step MFMAs each) -------
        v16f av[4];
#pragma unroll
        for (int il = 0; il < 4; ++il) {
            av[il] = __builtin_amdgcn_mfma_f32_32x32x16_f16(af[0], gB[il][0], z16, 0, 0, 0);
            av[il] = __builtin_amdgcn_mfma_f32_32x32x16_f16(af[1], gB[il][1], av[il], 0, 0, 0);
        }
        if (d < DD - 1) {              // prefetch d+1 (overlaps stores + phase 2)
#pragma unroll
            for (int ks = 0; ks < 2; ++ks)
                af[ks] = *(const v8h*)(fb + (d + 1) * MM + 16 * ks + 8 * h);
            const size_t gb = gc + (size_t)(d + 1) * 32768;
#pragma unroll
            for (int il = 0; il < 4; ++il)
#pragma unroll
                for (int ks = 0; ks < 2; ++ks)
                    gB[il][ks] = *(const v8h*)(g_h + gb +
                        ((size_t)(((4 * w + il) * 2 + ks) * 64) + lane) * 8);
        }
        // store cores: L[b][j=col][i], i = 4w..4w+3 packed as one b64
#pragma unroll
        for (int r16 = 0; r16 < 16; ++r16) {
            const int b = (r16 & 3) + 8 * (r16 >> 2) + 4 * h;
            H4 hv;
            hv.e[0] = (_Float16)av[0][r16];
            hv.e[1] = (_Float16)av[1][r16];
            hv.e[2] = (_Float16)av[2][r16];
            hv.e[3] = (_Float16)av[3][r16];
            *(uint2*)(lds + b * BSTR + col * ISTR + 4 * w) =
                make_uint2(hv.u[0], hv.u[1]);
        }
        __syncthreads();   // cores ready
        // ---- phase 2: wave w advances chains b-local = 4w..4w+3 ----------
#pragma unroll
        for (int cc = 0; cc < 4; ++cc) {
            _Float16* base = lds + (4 * w + cc) * BSTR;
            if (d == 0) {
                // init S_0 = C_0^T as B-frag: sb[ks][r] = C0[col][16ks+8h+r]
                //   = L[b][j=16ks+8h+r][i=col]   (one-time scalar reads)
#pragma unroll
                for (int ks = 0; ks < 2; ++ks) {
                    H8 x;
#pragma unroll
                    for (int r = 0; r < 8; ++r)
                        x.e[r] = base[(16 * ks + 8 * h + r) * ISTR + col];
                    sb[cc][ks] = x.h;
                }
            } else {
                // A = C_d^T: A[row=col][k=i] = L[b][col][i], b128 per K-step
                v8h a0 = *(const v8h*)(base + col * ISTR + 8 * h);
                v8h a1 = *(const v8h*)(base + col * ISTR + 16 + 8 * h);
                v16f acc;
                acc = __builtin_amdgcn_mfma_f32_32x32x16_f16(a0, sb[cc][0], z16, 0, 0, 0);
                acc = __builtin_amdgcn_mfma_f32_32x32x16_f16(a1, sb[cc][1], acc, 0, 0, 0);
                if (d == DD - 1) {
                    // trace: diagonal of S_15 (row == col lanes), reduce
                    float ts = 0.f;
#pragma unroll
                    for (int r16 = 0; r16 < 16; ++r16) {
                        const int row = (r16 & 3) + 8 * (r16 >> 2) + 4 * h;
                        if (row == col) ts += acc[r16];
                    }
#pragma unroll
                    for (int off = 32; off > 0; off >>= 1)
                        ts += __shfl_xor(ts, off);
                    if (lane == 0)
                        trout[(size_t)(b0 + 4 * w + cc) * CC + c] = ts;
                } else {
                    // rebuild state B-frags in registers:
                    // C-layout rows {0-3,8-11,16-19,24-27}+4h  ->  B-frag
                    // rows 8h..8h+7 / 16+8h.. : lane<->lane+32 half exchange
                    const unsigned A0 = pk2(acc[0],  acc[1]);
                    const unsigned A1 = pk2(acc[2],  acc[3]);
                    const unsigned B0 = pk2(acc[4],  acc[5]);
                    const unsigned B1 = pk2(acc[6],  acc[7]);
                    const unsigned C0 = pk2(acc[8],  acc[9]);
                    const unsigned C1 = pk2(acc[10], acc[11]);
                    const unsigned D0 = pk2(acc[12], acc[13]);
                    const unsigned D1 = pk2(acc[14], acc[15]);
                    const unsigned pA0 = (unsigned)__shfl_xor((int)A0, 32);
                    const unsigned pA1 = (unsigned)__shfl_xor((int)A1, 32);
                    const unsigned pB0 = (unsigned)__shfl_xor((int)B0, 32);
                    const unsigned pB1 = (unsigned)__shfl_xor((int)B1, 32);
                    const unsigned pC0 = (unsigned)__shfl_xor((int)C0, 32);
                    const unsigned pC1 = (unsigned)__shfl_xor((int)C1, 32);
                    const unsigned pD0 = (unsigned)__shfl_xor((int)D0, 32);
                    const unsigned pD1 = (unsigned)__shfl_xor((int)D1, 32);
                    H8 s0, s1;
                    s0.u[0] = h ? pB0 : A0;  s0.u[1] = h ? pB1 : A1;
                    s0.u[2] = h ? B0 : pA0;  s0.u[3] = h ? B1 : pA1;
                    s1.u[0] = h ? pD0 : C0;  s1.u[1] = h ? pD1 : C1;
                    s1.u[2] = h ? D0 : pC0;  s1.u[3] = h ? D1 : pC1;
                    sb[cc][0] = s0.h;
                    sb[cc][1] = s1.h;
                }
            }
        }
    }
}

// ---------------------------------------------------------------------------
// Kernel 3: tiny log-softmax over the [B][C] trace buffer (20 KB).
// ---------------------------------------------------------------------------
__global__ __launch_bounds__(256) void lsm_kernel(
    const float* __restrict__ tr, float* __restrict__ out) {
    const int b = blockIdx.x * 256 + threadIdx.x;   // 2 blocks x 256 = 512
    float v[CC];
    float mx = -1e30f;
#pragma unroll
    for (int c = 0; c < CC; ++c) {
        v[c] = tr[b * CC + c];
        mx = fmaxf(mx, v[c]);
    }
    float ssum = 0.f;
#pragma unroll
    for (int c = 0; c < CC; ++c) ssum += expf(v[c] - mx);
    const float ls = logf(ssum);
#pragma unroll
    for (int c = 0; c < CC; ++c) out[b * CC + c] = v[c] - mx - ls;
}

// ---------------------------------------------------------------------------
extern "C" void kernel_launch(void* const* d_in, const int* in_sizes, int n_in,
                              void* d_out, int out_size, void* d_ws, size_t ws_size,
                              hipStream_t stream) {
    const float* tensor = (const float*)d_in[0];
    const float* W      = (const float*)d_in[1];
    const float* bias   = (const float*)d_in[2];
    const float* G      = (const float*)d_in[3];
    float* out = (float*)d_out;

    const size_t FEAT = (size_t)BB * DD * MM;          // 262144 halves
    const size_t GPK  = (size_t)CC * DD * 64 * 64 * 8; // 5242880 halves
    _Float16* fh = (_Float16*)d_ws;
    _Float16* gh = fh + FEAT;
    float* trbuf = (float*)(gh + GPK);                 // 512*10 fp32 (20 KB)

    produce_kernel<<<1024 + 320, 256, 0, stream>>>(tensor, W, bias, G, fh, gh);
    chain_kernel<<<160, 512, 0, stream>>>(fh, gh, trbuf);
    lsm_kernel<<<BB / 256, 256, 0, stream>>>(trbuf, out);
}

// Round 7
// 116.605 us; speedup vs baseline: 1.0328x; 1.0328x over previous
//
#include <hip/hip_runtime.h>
#include <math.h>

#define BB 512
#define DD 16
#define NN 64
#define MM 32
#define RR 32
#define CC 10
#define ISTR 40          // halves per (b,j) row: 32 i + 8 pad (80 B, 16B-aligned)
#define BSTR 1288        // halves per b region: 32*ISTR + 8 (bank de-phase pad)

typedef _Float16 v8h __attribute__((ext_vector_type(8)));
typedef float v4f __attribute__((ext_vector_type(4)));
typedef float v16f __attribute__((ext_vector_type(16)));

union H8 { unsigned int u[4]; v8h h; _Float16 e[8]; };
union H4 { unsigned int u[2]; _Float16 e[4]; };

__device__ inline unsigned pk2(float a, float b) {
    union { unsigned u; _Float16 e[2]; } v;
    v.e[0] = (_Float16)a; v.e[1] = (_Float16)b;
    return v.u;
}

// ---------------------------------------------------------------------------
// Kernel 1: merged producers (coalesced via LDS staging).
//  blocks [0,1024):   feat_h = fp16( tensor @ W + b )   [B][D][M]
//  blocks [1024,1344): per (c,d,half-slab): G -> gh in 32x32x16 B-frag order:
//    tile t = i*2 + ks  (i in [0,32), ks = K-step)
//    gh[(((c*16+d)*64 + t)*64 + lane)*8 + r] =
//        fp16( G[c][d][i][ m = 16*ks + 8*(lane>>5) + r ][ j = lane&31 ] )
// ---------------------------------------------------------------------------
__global__ __launch_bounds__(256) void produce_kernel(
    const float* __restrict__ tensor, const float* __restrict__ W,
    const float* __restrict__ bias,   const float* __restrict__ G,
    _Float16* __restrict__ fh,        _Float16* __restrict__ gh) {
    __shared__ __align__(16) char smem[36864];
    const int t = threadIdx.x;
    if (blockIdx.x < 1024) {
        float* ten_s = (float*)smem;          // [8][64]
        float* W_s   = (float*)smem + 512;    // [64][32]
        const int bd0 = blockIdx.x * 8;
        if (t < 128)
            *(float4*)(ten_s + t * 4) = *(const float4*)(tensor + bd0 * NN + t * 4);
        *(float4*)(W_s + t * 4)        = *(const float4*)(W + t * 4);
        *(float4*)(W_s + 1024 + t * 4) = *(const float4*)(W + 1024 + t * 4);
        __syncthreads();
        const int m = t & 31, bd_l = t >> 5;
        float acc = bias[m];
#pragma unroll
        for (int n = 0; n < NN; ++n) acc += ten_s[bd_l * NN + n] * W_s[n * MM + m];
        fh[(bd0 + bd_l) * MM + m] = (_Float16)acc;
    } else {
        _Float16* lg = (_Float16*)smem;       // [di][m][j], m-stride 36 halves
        const int pb = blockIdx.x - 1024;     // 0..319
        const int c  = pb >> 5;
        const int d  = (pb >> 1) & 15;
        const int hf = pb & 1;
        const float* src = G + (size_t)(c * DD + d) * 32768 + hf * 16384;
#pragma unroll
        for (int k = 0; k < 16; ++k) {        // coalesced read of 64 KB slab-half
            const int f = (k * 256 + t) * 4;
            float4 v = *(const float4*)(src + f);
            const int di = f >> 10, m = (f >> 5) & 31, j = f & 31;
            H4 hv;
            hv.e[0] = (_Float16)v.x; hv.e[1] = (_Float16)v.y;
            hv.e[2] = (_Float16)v.z; hv.e[3] = (_Float16)v.w;
            *(uint2*)(lg + di * 1152 + m * 36 + j) = make_uint2(hv.u[0], hv.u[1]);
        }
        __syncthreads();
#pragma unroll
        for (int k = 0; k < 8; ++k) {         // coalesced 16B fragment writes
            const int idx = k * 256 + t;
            const int tl = idx >> 6, ln = idx & 63;   // tl = di*2 + ks
            const int di = tl >> 1, ks = tl & 1;
            const int hh = ln >> 5, j = ln & 31;
            H8 o;
#pragma unroll
            for (int r = 0; r < 8; ++r)
                o.e[r] = lg[di * 1152 + (16 * ks + 8 * hh + r) * 36 + j];
            const size_t gi = ((size_t)(c * DD + d) * 64 + hf * 32 + tl) * 64 + ln;
            *(v8h*)(gh + gi * 8) = o.h;
        }
    }
}

// ---------------------------------------------------------------------------
// Kernel 2 (fused, 32x32 MFMA, register state, SHUFFLE-FREE recurrence):
// per (c, 32 b's): all 16 d's + trace. S_d = C_d^T S_{d-1}, S_init = I,
// logits = diag-sum of S_15 (= tr Ptot).
// k-axis permutation trick: contract over slots with both operands permuted
// by pi(h,ks,r) = (r&3)+8(r>>2)+16ks+4h (exactly the rows the 32x32 C-layout
// accumulator already holds per lane-half). Consequences:
//  - state rebuild = 8 pk2 of consecutive acc elems (NO shfl/bpermute —
//    the 32 serialized ds_bpermute per wave-d were the round-6 stall);
//  - phase-1 stores core columns at permuted slot p = 4*perm(w)+il,
//    perm = [0,2,1,3,4,6,5,7] (bit0<->bit1 swap, a per-wave constant);
//  - the phase-2 A-read stays the same two b128 reads (+8h, +16+8h);
//  - init S = I in pseudo-B form; d=0 runs the uniform phase-2 path.
// Grid 160 (1 block/CU); same-c blocks pinned per XCD for gh L2 reuse.
// ---------------------------------------------------------------------------
__global__ __launch_bounds__(512, 2) void chain_kernel(
    const _Float16* __restrict__ feat_h,
    const _Float16* __restrict__ g_h,
    float* __restrict__ trout)         // [B][C] fp32 traces
{
    __shared__ __align__(16) _Float16 lds[32 * BSTR];   // 82432 B

    const int bid = blockIdx.x;        // 0..159
    const int xcd = bid & 7;
    const int idx = bid >> 3;          // 0..19
    int c, sub;
    if (idx < 16) { c = xcd; sub = idx; }
    else {
        const int e = idx - 16;        // 0..3
        c = 8 + (xcd >> 2);            // c8 on XCD 0-3, c9 on XCD 4-7
        sub = (xcd & 3) * 4 + e;       // 0..15
    }
    const int b0 = sub * 32;
    const int t    = threadIdx.x;
    const int w    = t >> 6;           // wave 0..7
    const int lane = t & 63;
    const int h    = lane >> 5;        // lane half
    const int col  = lane & 31;

    const int wp4 = 4 * ((w & 4) | ((w & 1) << 1) | ((w & 2) >> 1));  // 4*perm(w)

    const size_t gc = (size_t)c * DD * 32768;
    const _Float16* fb = feat_h + (size_t)(b0 + col) * (DD * MM);

    const v16f z16 = {0.f,0.f,0.f,0.f,0.f,0.f,0.f,0.f,
                      0.f,0.f,0.f,0.f,0.f,0.f,0.f,0.f};

    // prefetch d=0 fragments
    v8h af[2];                         // feat A-frags (32 b rows), per K-step
#pragma unroll
    for (int ks = 0; ks < 2; ++ks)
        af[ks] = *(const v8h*)(fb + 16 * ks + 8 * h);
    v8h gB[4][2];                      // G B-frags, i = 4w+il, per K-step
#pragma unroll
    for (int il = 0; il < 4; ++il)
#pragma unroll
        for (int ks = 0; ks < 2; ++ks)
            gB[il][ks] = *(const v8h*)(g_h + gc +
                ((size_t)(((4 * w + il) * 2 + ks) * 64) + lane) * 8);

    // init state = identity in pseudo-B form: slot (h,ks,r) holds I[pi][col]
    v8h sb[4][2];                      // [chain cc][K-step]
    {
        H8 x0, x1;
#pragma unroll
        for (int r = 0; r < 8; ++r) {
            const int pi = (r & 3) + 8 * (r >> 2) + 4 * h;
            x0.e[r] = (_Float16)((pi == col) ? 1.0f : 0.0f);
            x1.e[r] = (_Float16)((pi + 16 == col) ? 1.0f : 0.0f);
        }
#pragma unroll
        for (int cc = 0; cc < 4; ++cc) { sb[cc][0] = x0.h; sb[cc][1] = x1.h; }
    }

    for (int d = 0; d < DD; ++d) {
        __syncthreads();   // WAR: previous phase-2 A-reads of lds done
        // ---- phase 1: cores for i = 4w..4w+3 (2 K-step MFMAs each) -------
        v16f av[4];
#pragma unroll
        for (int il = 0; il < 4; ++il) {
            av[il] = __builtin_amdgcn_mfma_f32_32x32x16_f16(af[0], gB[il][0], z16, 0, 0, 0);
            av[il] = __builtin_amdgcn_mfma_f32_32x32x16_f16(af[1], gB[il][1], av[il], 0, 0, 0);
        }
        if (d < DD - 1) {              // prefetch d+1 (overlaps stores + phase 2)
#pragma unroll
            for (int ks = 0; ks < 2; ++ks)
                af[ks] = *(const v8h*)(fb + (d + 1) * MM + 16 * ks + 8 * h);
            const size_t gb = gc + (size_t)(d + 1) * 32768;
#pragma unroll
            for (int il = 0; il < 4; ++il)
#pragma unroll
                for (int ks = 0; ks < 2; ++ks)
                    gB[il][ks] = *(const v8h*)(g_h + gb +
                        ((size_t)(((4 * w + il) * 2 + ks) * 64) + lane) * 8);
        }
        // store cores at PERMUTED slot: L[b][j=col][p = wp4+il] (one b64)
#pragma unroll
        for (int r16 = 0; r16 < 16; ++r16) {
            const int b = (r16 & 3) + 8 * (r16 >> 2) + 4 * h;
            H4 hv;
            hv.e[0] = (_Float16)av[0][r16];
            hv.e[1] = (_Float16)av[1][r16];
            hv.e[2] = (_Float16)av[2][r16];
            hv.e[3] = (_Float16)av[3][r16];
            *(uint2*)(lds + b * BSTR + col * ISTR + wp4) =
                make_uint2(hv.u[0], hv.u[1]);
        }
        __syncthreads();   // cores ready
        // ---- phase 2: wave w advances chains b-local = 4w..4w+3 ----------
#pragma unroll
        for (int cc = 0; cc < 4; ++cc) {
            _Float16* base = lds + (4 * w + cc) * BSTR;
            // A slots (h,ks,r): permuted store makes these two b128 reads
            v8h a0 = *(const v8h*)(base + col * ISTR + 8 * h);
            v8h a1 = *(const v8h*)(base + col * ISTR + 16 + 8 * h);
            v16f acc;
            acc = __builtin_amdgcn_mfma_f32_32x32x16_f16(a0, sb[cc][0], z16, 0, 0, 0);
            acc = __builtin_amdgcn_mfma_f32_32x32x16_f16(a1, sb[cc][1], acc, 0, 0, 0);
            if (d == DD - 1) {
                // trace: diagonal of S_15 (standard C-layout), reduce
                float ts = 0.f;
#pragma unroll
                for (int r16 = 0; r16 < 16; ++r16) {
                    const int row = (r16 & 3) + 8 * (r16 >> 2) + 4 * h;
                    if (row == col) ts += acc[r16];
                }
#pragma unroll
                for (int off = 32; off > 0; off >>= 1)
                    ts += __shfl_xor(ts, off);
                if (lane == 0)
                    trout[(size_t)(b0 + 4 * w + cc) * CC + c] = ts;
            } else {
                // rebuild pseudo-B state: slot (ks,r) <- acc[r + 8ks]
                H8 s0, s1;
                s0.u[0] = pk2(acc[0],  acc[1]);
                s0.u[1] = pk2(acc[2],  acc[3]);
                s0.u[2] = pk2(acc[4],  acc[5]);
                s0.u[3] = pk2(acc[6],  acc[7]);
                s1.u[0] = pk2(acc[8],  acc[9]);
                s1.u[1] = pk2(acc[10], acc[11]);
                s1.u[2] = pk2(acc[12], acc[13]);
                s1.u[3] = pk2(acc[14], acc[15]);
                sb[cc][0] = s0.h;
                sb[cc][1] = s1.h;
            }
        }
    }
}

// ---------------------------------------------------------------------------
// Kernel 3: tiny log-softmax over the [B][C] trace buffer (20 KB).
// ---------------------------------------------------------------------------
__global__ __launch_bounds__(256) void lsm_kernel(
    const float* __restrict__ tr, float* __restrict__ out) {
    const int b = blockIdx.x * 256 + threadIdx.x;   // 2 blocks x 256 = 512
    float v[CC];
    float mx = -1e30f;
#pragma unroll
    for (int c = 0; c < CC; ++c) {
        v[c] = tr[b * CC + c];
        mx = fmaxf(mx, v[c]);
    }
    float ssum = 0.f;
#pragma unroll
    for (int c = 0; c < CC; ++c) ssum += expf(v[c] - mx);
    const float ls = logf(ssum);
#pragma unroll
    for (int c = 0; c < CC; ++c) out[b * CC + c] = v[c] - mx - ls;
}

// ---------------------------------------------------------------------------
extern "C" void kernel_launch(void* const* d_in, const int* in_sizes, int n_in,
                              void* d_out, int out_size, void* d_ws, size_t ws_size,
                              hipStream_t stream) {
    const float* tensor = (const float*)d_in[0];
    const float* W      = (const float*)d_in[1];
    const float* bias   = (const float*)d_in[2];
    const float* G      = (const float*)d_in[3];
    float* out = (float*)d_out;

    const size_t FEAT = (size_t)BB * DD * MM;          // 262144 halves
    const size_t GPK  = (size_t)CC * DD * 64 * 64 * 8; // 5242880 halves
    _Float16* fh = (_Float16*)d_ws;
    _Float16* gh = fh + FEAT;
    float* trbuf = (float*)(gh + GPK);                 // 512*10 fp32 (20 KB)

    produce_kernel<<<1024 + 320, 256, 0, stream>>>(tensor, W, bias, G, fh, gh);
    chain_kernel<<<160, 512, 0, stream>>>(fh, gh, trbuf);
    lsm_kernel<<<BB / 256, 256, 0, stream>>>(trbuf, out);
}

// Round 10
// 110.523 us; speedup vs baseline: 1.0897x; 1.0550x over previous
//
#include <hip/hip_runtime.h>
#include <math.h>

#define BB 512
#define DD 16
#define NN 64
#define MM 32
#define RR 32
#define CC 10
#define ISTR 40          // halves per (b,j) row: 32 i + 8 pad (80 B, 16B-aligned)
#define BSTR 1288        // halves per b region: 32*ISTR + 8 (bank de-phase pad)

typedef _Float16 v8h __attribute__((ext_vector_type(8)));
typedef float v4f __attribute__((ext_vector_type(4)));
typedef float v16f __attribute__((ext_vector_type(16)));

union H8 { unsigned int u[4]; v8h h; _Float16 e[8]; };
union H4 { unsigned int u[2]; _Float16 e[4]; };

__device__ inline unsigned pk2(float a, float b) {
    union { unsigned u; _Float16 e[2]; } v;
    v.e[0] = (_Float16)a; v.e[1] = (_Float16)b;
    return v.u;
}

// ---------------------------------------------------------------------------
// Kernel 1: merged producers (coalesced via LDS staging).
//  blocks [0,1024):   feat_h = fp16( tensor @ W + b )   [B][D][M]
//  blocks [1024,1344): per (c,d,half-slab): G -> gh in 32x32x16 B-frag order
// ---------------------------------------------------------------------------
__global__ __launch_bounds__(256) void produce_kernel(
    const float* __restrict__ tensor, const float* __restrict__ W,
    const float* __restrict__ bias,   const float* __restrict__ G,
    _Float16* __restrict__ fh,        _Float16* __restrict__ gh) {
    __shared__ __align__(16) char smem[36864];
    const int t = threadIdx.x;
    if (blockIdx.x < 1024) {
        float* ten_s = (float*)smem;          // [8][64]
        float* W_s   = (float*)smem + 512;    // [64][32]
        const int bd0 = blockIdx.x * 8;
        if (t < 128)
            *(float4*)(ten_s + t * 4) = *(const float4*)(tensor + bd0 * NN + t * 4);
        *(float4*)(W_s + t * 4)        = *(const float4*)(W + t * 4);
        *(float4*)(W_s + 1024 + t * 4) = *(const float4*)(W + 1024 + t * 4);
        __syncthreads();
        const int m = t & 31, bd_l = t >> 5;
        float acc = bias[m];
#pragma unroll
        for (int n = 0; n < NN; ++n) acc += ten_s[bd_l * NN + n] * W_s[n * MM + m];
        fh[(bd0 + bd_l) * MM + m] = (_Float16)acc;
    } else {
        _Float16* lg = (_Float16*)smem;       // [di][m][j], m-stride 36 halves
        const int pb = blockIdx.x - 1024;     // 0..319
        const int c  = pb >> 5;
        const int d  = (pb >> 1) & 15;
        const int hf = pb & 1;
        const float* src = G + (size_t)(c * DD + d) * 32768 + hf * 16384;
#pragma unroll
        for (int k = 0; k < 16; ++k) {        // coalesced read of 64 KB slab-half
            const int f = (k * 256 + t) * 4;
            float4 v = *(const float4*)(src + f);
            const int di = f >> 10, m = (f >> 5) & 31, j = f & 31;
            H4 hv;
            hv.e[0] = (_Float16)v.x; hv.e[1] = (_Float16)v.y;
            hv.e[2] = (_Float16)v.z; hv.e[3] = (_Float16)v.w;
            *(uint2*)(lg + di * 1152 + m * 36 + j) = make_uint2(hv.u[0], hv.u[1]);
        }
        __syncthreads();
#pragma unroll
        for (int k = 0; k < 8; ++k) {         // coalesced 16B fragment writes
            const int idx = k * 256 + t;
            const int tl = idx >> 6, ln = idx & 63;   // tl = di*2 + ks
            const int di = tl >> 1, ks = tl & 1;
            const int hh = ln >> 5, j = ln & 31;
            H8 o;
#pragma unroll
            for (int r = 0; r < 8; ++r)
                o.e[r] = lg[di * 1152 + (16 * ks + 8 * hh + r) * 36 + j];
            const size_t gi = ((size_t)(c * DD + d) * 64 + hf * 32 + tl) * 64 + ln;
            *(v8h*)(gh + gi * 8) = o.h;
        }
    }
}

// ---------------------------------------------------------------------------
// Kernel 2: per (c, 16 b's, d-segment s): 8 chain steps, write segment
// product to mbuf. S_d = C_d^T S_{d-1}, S_init = I -> S_8 = P_s^T (C-layout).
//  s=0: in-LDS transpose (uint2-packed) -> M0 = P0 row-major
//  s=1: 16 scalar LDS writes at [row][col] -> M1 = P1^T row-major
// then tr(P0 P1) = sum elementwise M0 .* M1 in the combine kernel.
// Grid 640 (10c x 32 subs x 2 segs), 512 thr, 41 KB LDS, 2 blocks/CU
// co-resident (launch_bounds (512,4)) => cross-block overlap hides the
// lockstep per-d latency that capped the 160-block variants at ~40 us.
// No cross-block sync: both blocks write M; combine kernel does the dot.
// LDS staging readback guarded by sched_barrier + lgkmcnt(0) (R1-verified
// pattern; round-8's unguarded uint2-store/v8h-load pair is the presumed
// TBAA reorder that corrupted M).
// ---------------------------------------------------------------------------
__global__ __launch_bounds__(512, 4) void chain_kernel(
    const _Float16* __restrict__ feat_h,
    const _Float16* __restrict__ g_h,
    _Float16* __restrict__ mbuf)       // [2][C][32][16][1024] fp16
{
    __shared__ __align__(16) _Float16 lds[16 * BSTR];   // 41216 B

    const int bid = blockIdx.x;        // 0..639
    const int xcd = bid & 7;
    const int idx = bid >> 3;          // 0..79
    int c, unit;
    if (idx < 64) { c = xcd; unit = idx; }
    else {
        const int e = idx - 64;        // 0..15
        c = 8 + (xcd >> 2);            // c8 on XCD 0-3, c9 on XCD 4-7
        unit = (xcd & 3) * 16 + e;     // 0..63
    }
    const int s   = unit & 1;          // d-segment
    const int sub = unit >> 1;         // 0..31
    const int b0  = sub * 16;

    const int t    = threadIdx.x;
    const int w    = t >> 6;           // wave 0..7
    const int lane = t & 63;
    const int h    = lane >> 5;        // lane half
    const int col  = lane & 31;

    const int wp4 = 4 * ((w & 4) | ((w & 1) << 1) | ((w & 2) >> 1));  // 4*perm(w)

    const size_t gc = (size_t)c * DD * 32768;
    // A rows 16-31 duplicate 0-15 (only b<16 kept) -> no OOB
    const _Float16* fb = feat_h + (size_t)(b0 + (col & 15)) * (DD * MM);

    const v16f z16 = {0.f,0.f,0.f,0.f,0.f,0.f,0.f,0.f,
                      0.f,0.f,0.f,0.f,0.f,0.f,0.f,0.f};

    const int d0 = 8 * s;

    // prefetch d0 fragments
    v8h af[2];
#pragma unroll
    for (int ks = 0; ks < 2; ++ks)
        af[ks] = *(const v8h*)(fb + d0 * MM + 16 * ks + 8 * h);
    v8h gB[4][2];
#pragma unroll
    for (int il = 0; il < 4; ++il)
#pragma unroll
        for (int ks = 0; ks < 2; ++ks)
            gB[il][ks] = *(const v8h*)(g_h + gc + (size_t)d0 * 32768 +
                ((size_t)(((4 * w + il) * 2 + ks) * 64) + lane) * 8);

    // init state = identity in pseudo-B form: slot (h,ks,r) holds I[pi][col]
    v8h sb[2][2];                      // [chain cc][K-step]
    {
        H8 x0, x1;
#pragma unroll
        for (int r = 0; r < 8; ++r) {
            const int pi = (r & 3) + 8 * (r >> 2) + 4 * h;
            x0.e[r] = (_Float16)((pi == col) ? 1.0f : 0.0f);
            x1.e[r] = (_Float16)((pi + 16 == col) ? 1.0f : 0.0f);
        }
#pragma unroll
        for (int cc = 0; cc < 2; ++cc) { sb[cc][0] = x0.h; sb[cc][1] = x1.h; }
    }

    for (int dd = 0; dd < 8; ++dd) {
        const int d = d0 + dd;
        __syncthreads();   // WAR: previous phase-2 LDS use done
        // ---- phase 1: cores for i = 4w..4w+3 (2 K-step MFMAs each) -------
        v16f av[4];
#pragma unroll
        for (int il = 0; il < 4; ++il) {
            av[il] = __builtin_amdgcn_mfma_f32_32x32x16_f16(af[0], gB[il][0], z16, 0, 0, 0);
            av[il] = __builtin_amdgcn_mfma_f32_32x32x16_f16(af[1], gB[il][1], av[il], 0, 0, 0);
        }
        if (dd < 7) {                  // prefetch d+1 (overlaps stores + phase 2)
#pragma unroll
            for (int ks = 0; ks < 2; ++ks)
                af[ks] = *(const v8h*)(fb + (d + 1) * MM + 16 * ks + 8 * h);
            const size_t gb = gc + (size_t)(d + 1) * 32768;
#pragma unroll
            for (int il = 0; il < 4; ++il)
#pragma unroll
                for (int ks = 0; ks < 2; ++ks)
                    gB[il][ks] = *(const v8h*)(g_h + gb +
                        ((size_t)(((4 * w + il) * 2 + ks) * 64) + lane) * 8);
        }
        // store cores at PERMUTED slot: L[b][j=col][p = wp4..wp4+3] (b64),
        // only local b < 16 (r16 < 8)
#pragma unroll
        for (int r16 = 0; r16 < 8; ++r16) {
            const int b = (r16 & 3) + 8 * (r16 >> 2) + 4 * h;
            H4 hv;
            hv.e[0] = (_Float16)av[0][r16];
            hv.e[1] = (_Float16)av[1][r16];
            hv.e[2] = (_Float16)av[2][r16];
            hv.e[3] = (_Float16)av[3][r16];
            *(uint2*)(lds + b * BSTR + col * ISTR + wp4) =
                make_uint2(hv.u[0], hv.u[1]);
        }
        __syncthreads();   // cores ready
        // ---- phase 2: wave w advances chains b-local = 2w, 2w+1 ----------
#pragma unroll
        for (int cc = 0; cc < 2; ++cc) {
            _Float16* base = lds + (2 * w + cc) * BSTR;
            v8h a0 = *(const v8h*)(base + col * ISTR + 8 * h);
            v8h a1 = *(const v8h*)(base + col * ISTR + 16 + 8 * h);
            v16f acc;
            acc = __builtin_amdgcn_mfma_f32_32x32x16_f16(a0, sb[cc][0], z16, 0, 0, 0);
            acc = __builtin_amdgcn_mfma_f32_32x32x16_f16(a1, sb[cc][1], acc, 0, 0, 0);
            if (dd == 7) {
                // stage M into own (dead) core region, halves 0..1023
                if (s == 0) {
                    // T[col*32+row] = X[row][col]  (X = P0^T) -> M0 = P0
#pragma unroll
                    for (int g = 0; g < 4; ++g) {
                        const unsigned lo = pk2(acc[4 * g + 0], acc[4 * g + 1]);
                        const unsigned hi = pk2(acc[4 * g + 2], acc[4 * g + 3]);
                        *(uint2*)(base + col * 32 + 8 * g + 4 * h) =
                            make_uint2(lo, hi);
                    }
                } else {
                    // T[row*32+col] = X[row][col]  (X = P1^T) -> M1 = P1^T
#pragma unroll
                    for (int r16 = 0; r16 < 16; ++r16) {
                        const int row = (r16 & 3) + 8 * (r16 >> 2) + 4 * h;
                        base[row * 32 + col] = (_Float16)acc[r16];
                    }
                }
                __builtin_amdgcn_sched_barrier(0);
                asm volatile("s_waitcnt lgkmcnt(0)" ::: "memory");
                __builtin_amdgcn_sched_barrier(0);
                const v8h mlo = *(const v8h*)(base + lane * 16);
                const v8h mhi = *(const v8h*)(base + lane * 16 + 8);
                _Float16* mb = mbuf + ((((size_t)s * CC + c) * 32 + sub) * 16 +
                                       (2 * w + cc)) * 1024;
                *(v8h*)(mb + lane * 16)     = mlo;
                *(v8h*)(mb + lane * 16 + 8) = mhi;
            } else {
                // rebuild pseudo-B state: slot (ks,r) <- acc[r + 8ks]
                H8 s0, s1;
                s0.u[0] = pk2(acc[0],  acc[1]);
                s0.u[1] = pk2(acc[2],  acc[3]);
                s0.u[2] = pk2(acc[4],  acc[5]);
                s0.u[3] = pk2(acc[6],  acc[7]);
                s1.u[0] = pk2(acc[8],  acc[9]);
                s1.u[1] = pk2(acc[10], acc[11]);
                s1.u[2] = pk2(acc[12], acc[13]);
                s1.u[3] = pk2(acc[14], acc[15]);
                sb[cc][0] = s0.h;
                sb[cc][1] = s1.h;
            }
        }
    }
}

// ---------------------------------------------------------------------------
// Kernel 3: fused combine + log-softmax (R1-verified structure). Wave per b:
//   tr[c] = sum_rc M0[r][c] * M1[r][c]   (M1 = P1^T -> pure elementwise dot)
// ---------------------------------------------------------------------------
__global__ __launch_bounds__(128) void combine_lsm_kernel(
    const _Float16* __restrict__ mbuf, float* __restrict__ out) {
    const int t    = threadIdx.x;
    const int b    = blockIdx.x * 2 + (t >> 6);
    const int lane = t & 63;

    float tr[CC];
#pragma unroll
    for (int c = 0; c < CC; ++c) {
        const _Float16* p0 = mbuf +
            (((size_t)c * 32 + (b >> 4)) * 16 + (b & 15)) * 1024 + lane * 16;
        const _Float16* p1 = mbuf +
            ((((size_t)CC + c) * 32 + (b >> 4)) * 16 + (b & 15)) * 1024 + lane * 16;
        v8h x0 = ((const v8h*)p0)[0];
        v8h x1 = ((const v8h*)p0)[1];
        v8h y0 = ((const v8h*)p1)[0];
        v8h y1 = ((const v8h*)p1)[1];
        float acc = 0.f;
#pragma unroll
        for (int e = 0; e < 8; ++e)
            acc += (float)x0[e] * (float)y0[e] + (float)x1[e] * (float)y1[e];
#pragma unroll
        for (int off = 32; off > 0; off >>= 1)
            acc += __shfl_xor(acc, off);
        tr[c] = acc;
    }
    float mx = -1e30f;
#pragma unroll
    for (int c = 0; c < CC; ++c) mx = fmaxf(mx, tr[c]);
    float ssum = 0.f;
#pragma unroll
    for (int c = 0; c < CC; ++c) ssum += expf(tr[c] - mx);
    const float ls = logf(ssum);
    float val = 0.f;
#pragma unroll
    for (int c = 0; c < CC; ++c) if (lane == c) val = tr[c] - mx - ls;
    if (lane < CC) out[b * CC + lane] = val;
}

// ---------------------------------------------------------------------------
extern "C" void kernel_launch(void* const* d_in, const int* in_sizes, int n_in,
                              void* d_out, int out_size, void* d_ws, size_t ws_size,
                              hipStream_t stream) {
    const float* tensor = (const float*)d_in[0];
    const float* W      = (const float*)d_in[1];
    const float* bias   = (const float*)d_in[2];
    const float* G      = (const float*)d_in[3];
    float* out = (float*)d_out;

    const size_t FEAT = (size_t)BB * DD * MM;          // 262144 halves
    const size_t GPK  = (size_t)CC * DD * 64 * 64 * 8; // 5242880 halves
    _Float16* fh   = (_Float16*)d_ws;
    _Float16* gh   = fh + FEAT;
    _Float16* mbuf = gh + GPK;                         // 2*10*32*16*1024 (20 MB)

    produce_kernel<<<1024 + 320, 256, 0, stream>>>(tensor, W, bias, G, fh, gh);
    chain_kernel<<<640, 512, 0, stream>>>(fh, gh, mbuf);
    combine_lsm_kernel<<<BB / 2, 128, 0, stream>>>(mbuf, out);
}